// Round 1
// baseline (26.446 us; speedup 1.0000x reference)
//
#include <hip/hip_runtime.h>

// Problem constants (from reference)
#define N_NODES 100000
#define PAD_DEG 32
#define BATCH 16384
#define K 11
#define F 128

// One wave (64 lanes) per batch row; 4 waves (256 threads) per block.
__global__ __launch_bounds__(256) void WeightedAggregator_89489938580181_kernel(
    const float* __restrict__ emb,   // [N_NODES, F]
    const int*   __restrict__ samp,  // [BATCH, K]
    const int*   __restrict__ adj,   // [N_NODES, PAD_DEG]
    float*       __restrict__ out)   // [BATCH, F]
{
    const int lane = threadIdx.x & 63;
    // wave id within block — readfirstlane so the compiler treats it (and b)
    // as wave-uniform, enabling scalar loads for samp[]
    const int wid  = __builtin_amdgcn_readfirstlane(threadIdx.x >> 6);
    const int b    = blockIdx.x * 4 + wid;
    if (b >= BATCH) return;

    // ---- load the 11 sampled node ids (wave-uniform scalar loads) ----
    int s[K];
#pragma unroll
    for (int v = 0; v < K; ++v)
        s[v] = samp[b * K + v];

    // ---- membership counts via ballot ----
    // lane layout: half = lane>>5 selects neighbor n = 2*p + half,
    //              d = lane&31 indexes the 32-wide adjacency list.
    const int half = lane >> 5;
    const int d    = lane & 31;

    int cnt[K];
#pragma unroll
    for (int v = 0; v < K; ++v) cnt[v] = 0;

#pragma unroll
    for (int p = 0; p < 6; ++p) {
        const int n = 2 * p + half;          // n in [0, 11]; n==11 invalid on p==5, half==1
        // -1 can never match: samp/adj values are in [0, N_NODES)
        const int a = (n < K) ? adj[s[n] * PAD_DEG + d] : -1;
#pragma unroll
        for (int v = 0; v < K; ++v) {
            const unsigned long long m = __ballot(a == s[v]);
            // low 32 bits -> member(n=2p, v); high 32 bits -> member(n=2p+1, v)
            cnt[v] += (int)((m & 0xFFFFFFFFull) != 0) + (int)((m >> 32) != 0);
        }
    }

    // ---- weights: w[v] = cnt[v] / sum(cnt)  (BETA = 1.0) ----
    int total = 0;
#pragma unroll
    for (int v = 0; v < K; ++v) total += cnt[v];
    const float inv = 1.0f / (float)total;   // total >= 11 (self-loop in adj slot 0)

    float w[K];
#pragma unroll
    for (int v = 0; v < K; ++v) w[v] = (float)cnt[v] * inv;

    // ---- weighted embedding gather: each lane owns 2 floats of the row ----
    float2 acc = make_float2(0.0f, 0.0f);
#pragma unroll
    for (int v = 0; v < K; ++v) {
        const float2 e = *reinterpret_cast<const float2*>(
            &emb[(size_t)s[v] * F + lane * 2]);
        acc.x = fmaf(w[v], e.x, acc.x);
        acc.y = fmaf(w[v], e.y, acc.y);
    }
    *reinterpret_cast<float2*>(&out[(size_t)b * F + lane * 2]) = acc;
}

extern "C" void kernel_launch(void* const* d_in, const int* in_sizes, int n_in,
                              void* d_out, int out_size, void* d_ws, size_t ws_size,
                              hipStream_t stream) {
    const float* emb  = (const float*)d_in[0];
    const int*   samp = (const int*)d_in[1];
    const int*   adj  = (const int*)d_in[2];
    float*       outp = (float*)d_out;

    const int rows_per_block = 4;                 // 4 waves of 64
    dim3 grid(BATCH / rows_per_block);            // 4096 blocks
    dim3 block(256);
    WeightedAggregator_89489938580181_kernel<<<grid, block, 0, stream>>>(
        emb, samp, adj, outp);
}

// Round 2
// 25.857 us; speedup vs baseline: 1.0228x; 1.0228x over previous
//
#include <hip/hip_runtime.h>

// Problem constants (from reference)
#define N_NODES 100000
#define PAD_DEG 32
#define BATCH 16384
#define K 11
#define F 128

// One wave (64 lanes) per batch row; 4 waves (256 threads) per block.
// Second launch_bounds arg = min waves per SIMD -> caps VGPR at 64,
// guaranteeing 8 waves/SIMD occupancy.
__global__ __launch_bounds__(256, 8) void WeightedAggregator_89489938580181_kernel(
    const float* __restrict__ emb,   // [N_NODES, F]
    const int*   __restrict__ samp,  // [BATCH, K]
    const int*   __restrict__ adj,   // [N_NODES, PAD_DEG]
    float*       __restrict__ out)   // [BATCH, F]
{
    const int lane = threadIdx.x & 63;
    // wave id within block — readfirstlane so the compiler treats it (and b)
    // as wave-uniform, enabling scalar loads for samp[]
    const int wid  = __builtin_amdgcn_readfirstlane(threadIdx.x >> 6);
    const int b    = blockIdx.x * 4 + wid;

    // ---- load the 11 sampled node ids (wave-uniform scalar loads) ----
    int s[K];
#pragma unroll
    for (int v = 0; v < K; ++v)
        s[v] = samp[b * K + v];

    // lane layout for membership: half = lane>>5 selects neighbor n = 2*p+half,
    //                             d = lane&31 indexes the 32-wide adjacency list.
    const int half = lane >> 5;
    const int d    = lane & 31;

    // ---- issue ALL gathers up front (addresses depend only on s[]) ----
    // 6 adjacency gathers (2 rows per wave-load via the half split)
    int a[6];
#pragma unroll
    for (int p = 0; p < 6; ++p) {
        const int n = 2 * p + half;          // n in [0, 11]; n==11 invalid (p==5, half==1)
        // -1 can never match: samp/adj values are in [0, N_NODES)
        a[p] = (n < K) ? adj[s[n] * PAD_DEG + d] : -1;
    }
    // 11 embedding-row gathers, 2 floats per lane (coalesced 512 B per row)
    float2 e[K];
#pragma unroll
    for (int v = 0; v < K; ++v) {
        e[v] = *reinterpret_cast<const float2*>(
            &emb[(size_t)s[v] * F + lane * 2]);
    }

    // ---- membership counts via ballot (pure VALU/SALU on registers) ----
    int cnt[K];
#pragma unroll
    for (int v = 0; v < K; ++v) cnt[v] = 0;

#pragma unroll
    for (int p = 0; p < 6; ++p) {
#pragma unroll
        for (int v = 0; v < K; ++v) {
            const unsigned long long m = __ballot(a[p] == s[v]);
            // low 32 bits -> member(n=2p, v); high 32 bits -> member(n=2p+1, v)
            cnt[v] += (int)((m & 0xFFFFFFFFull) != 0) + (int)((m >> 32) != 0);
        }
    }

    // ---- weights: w[v] = cnt[v] / sum(cnt)  (BETA = 1.0) ----
    int total = 0;
#pragma unroll
    for (int v = 0; v < K; ++v) total += cnt[v];
    const float inv = 1.0f / (float)total;   // total >= 11 (self-loop in adj slot 0)

    // ---- weighted sum on the prefetched embedding fragments ----
    float2 acc = make_float2(0.0f, 0.0f);
#pragma unroll
    for (int v = 0; v < K; ++v) {
        const float w = (float)cnt[v] * inv;
        acc.x = fmaf(w, e[v].x, acc.x);
        acc.y = fmaf(w, e[v].y, acc.y);
    }
    *reinterpret_cast<float2*>(&out[(size_t)b * F + lane * 2]) = acc;
}

extern "C" void kernel_launch(void* const* d_in, const int* in_sizes, int n_in,
                              void* d_out, int out_size, void* d_ws, size_t ws_size,
                              hipStream_t stream) {
    const float* emb  = (const float*)d_in[0];
    const int*   samp = (const int*)d_in[1];
    const int*   adj  = (const int*)d_in[2];
    float*       outp = (float*)d_out;

    const int rows_per_block = 4;                 // 4 waves of 64
    dim3 grid(BATCH / rows_per_block);            // 4096 blocks
    dim3 block(256);
    WeightedAggregator_89489938580181_kernel<<<grid, block, 0, stream>>>(
        emb, samp, adj, outp);
}

// Round 3
// 24.352 us; speedup vs baseline: 1.0860x; 1.0618x over previous
//
#include <hip/hip_runtime.h>

// Problem constants (from reference)
#define N_NODES 100000
#define PAD_DEG 32
#define BATCH 16384
#define K 11
#define F 128

// One wave (64 lanes) handles TWO batch rows: lanes 0-31 carry row A,
// lanes 32-63 carry row B, through the whole kernel:
//  - adj gather p: low half loads adj[sA[p]][0..31], high half adj[sB[p]][0..31]
//  - ballot(a[p]==ssel[v]): low 32 bits -> member(A,p,v), high 32 -> member(B,p,v)
//  - emb gather v: float4 per lane, low half = rowA's v-th emb row, high = rowB's
//  - store: one dwordx4 instruction writes both output rows (1 KB)
// 4 waves (256 threads) per block -> 8 rows/block, 2048 blocks.
__global__ __launch_bounds__(256, 6) void WeightedAggregator_89489938580181_kernel(
    const float* __restrict__ emb,   // [N_NODES, F]
    const int*   __restrict__ samp,  // [BATCH, K]
    const int*   __restrict__ adj,   // [N_NODES, PAD_DEG]
    float*       __restrict__ out)   // [BATCH, F]
{
    const int lane = threadIdx.x & 63;
    const int wid  = __builtin_amdgcn_readfirstlane(threadIdx.x >> 6);
    const int wave = blockIdx.x * 4 + wid;   // global wave id
    const int rA   = wave * 2;               // first batch row
    const int rB   = rA + 1;                 // second batch row

    // ---- sampled node ids for both rows (wave-uniform scalar loads) ----
    int sA[K], sB[K];
#pragma unroll
    for (int v = 0; v < K; ++v) sA[v] = samp[rA * K + v];
#pragma unroll
    for (int v = 0; v < K; ++v) sB[v] = samp[rB * K + v];

    const int half = lane >> 5;   // 0 -> row A, 1 -> row B
    const int d    = lane & 31;   // adjacency slot / column group

    // per-lane selected node ids: my row's sample v
    int ssel[K];
#pragma unroll
    for (int v = 0; v < K; ++v) ssel[v] = half ? sB[v] : sA[v];

    // ---- adjacency gathers: neighbor p's adj row for my batch row ----
    // (one instruction covers both rows: 2 x 128 B segments)
    int a[K];
#pragma unroll
    for (int p = 0; p < K; ++p)
        a[p] = adj[(size_t)ssel[p] * PAD_DEG + d];

    // ---- embedding gathers: float4/lane, 32 lanes per row, 2 rows/instr ----
    float4 e[K];
#pragma unroll
    for (int v = 0; v < K; ++v)
        e[v] = *reinterpret_cast<const float4*>(
            &emb[(size_t)ssel[v] * F + d * 4]);

    // ---- membership counts via ballot (both rows per ballot) ----
    int cA[K], cB[K];
#pragma unroll
    for (int v = 0; v < K; ++v) { cA[v] = 0; cB[v] = 0; }

#pragma unroll
    for (int p = 0; p < K; ++p) {
#pragma unroll
        for (int v = 0; v < K; ++v) {
            const unsigned long long m = __ballot(a[p] == ssel[v]);
            cA[v] += (int)(((unsigned)m) != 0);   // lanes 0-31: row A
            cB[v] += (int)((m >> 32) != 0);       // lanes 32-63: row B
        }
    }

    // ---- weights: w[v] = cnt[v] / sum(cnt)  (BETA = 1.0) ----
    int tA = 0, tB = 0;
#pragma unroll
    for (int v = 0; v < K; ++v) { tA += cA[v]; tB += cB[v]; }
    const float invA = 1.0f / (float)tA;   // totals >= 11 (self-loop in adj slot 0)
    const float invB = 1.0f / (float)tB;

    // ---- weighted sum on prefetched fragments (per-lane row select) ----
    float4 acc = make_float4(0.0f, 0.0f, 0.0f, 0.0f);
#pragma unroll
    for (int v = 0; v < K; ++v) {
        const float w = half ? (float)cB[v] * invB : (float)cA[v] * invA;
        acc.x = fmaf(w, e[v].x, acc.x);
        acc.y = fmaf(w, e[v].y, acc.y);
        acc.z = fmaf(w, e[v].z, acc.z);
        acc.w = fmaf(w, e[v].w, acc.w);
    }

    // ---- store: low half writes row A, high half writes row B (1 KB/wave) ----
    const int row = half ? rB : rA;
    *reinterpret_cast<float4*>(&out[(size_t)row * F + d * 4]) = acc;
}

extern "C" void kernel_launch(void* const* d_in, const int* in_sizes, int n_in,
                              void* d_out, int out_size, void* d_ws, size_t ws_size,
                              hipStream_t stream) {
    const float* emb  = (const float*)d_in[0];
    const int*   samp = (const int*)d_in[1];
    const int*   adj  = (const int*)d_in[2];
    float*       outp = (float*)d_out;

    const int rows_per_block = 8;                 // 4 waves x 2 rows
    dim3 grid(BATCH / rows_per_block);            // 2048 blocks
    dim3 block(256);
    WeightedAggregator_89489938580181_kernel<<<grid, block, 0, stream>>>(
        emb, samp, adj, outp);
}

// Round 4
// 24.086 us; speedup vs baseline: 1.0980x; 1.0110x over previous
//
#include <hip/hip_runtime.h>

// Problem constants (from reference)
#define N_NODES 100000
#define PAD_DEG 32
#define BATCH 16384
#define K 11
#define F 128

// One wave (64 lanes) handles FOUR batch rows: quarter q = lane>>4 owns
// row wave*4+q, d = lane&15 is the within-row lane.
//  - adj gather p: int2 per lane -> 16 lanes cover the 32-slot adj row;
//    one instruction loads 4 rows' adj lists (4 x 128 B segments).
//  - ballot(a.x==ssel[v] || a.y==ssel[v]): bits [16q,16q+16) give row q's
//    membership of sample v in neighbor p's adj list.
//  - emb gather v: two float4 per lane covering row halves; one instruction
//    loads 4 x 256 B contiguous segments.
//  - store: two float4 per lane, 4 x 256 B contiguous segments per instr.
// 4 waves (256 threads) per block -> 16 rows/block, 1024 blocks.
__global__ __launch_bounds__(256, 3) void WeightedAggregator_89489938580181_kernel(
    const float* __restrict__ emb,   // [N_NODES, F]
    const int*   __restrict__ samp,  // [BATCH, K]
    const int*   __restrict__ adj,   // [N_NODES, PAD_DEG]
    float*       __restrict__ out)   // [BATCH, F]
{
    const int lane = threadIdx.x & 63;
    const int wid  = __builtin_amdgcn_readfirstlane(threadIdx.x >> 6);
    const int wave = blockIdx.x * 4 + wid;   // global wave id
    const int r0   = wave * 4;               // first of 4 batch rows

    // ---- sampled node ids for all 4 rows (wave-uniform scalar loads) ----
    int s0[K], s1[K], s2[K], s3[K];
#pragma unroll
    for (int v = 0; v < K; ++v) s0[v] = samp[(r0 + 0) * K + v];
#pragma unroll
    for (int v = 0; v < K; ++v) s1[v] = samp[(r0 + 1) * K + v];
#pragma unroll
    for (int v = 0; v < K; ++v) s2[v] = samp[(r0 + 2) * K + v];
#pragma unroll
    for (int v = 0; v < K; ++v) s3[v] = samp[(r0 + 3) * K + v];

    const int q = lane >> 4;      // which row this lane serves
    const int d = lane & 15;      // within-row lane index

    // per-lane selected node ids: my row's sample v (2-level cndmask tree)
    int ssel[K];
#pragma unroll
    for (int v = 0; v < K; ++v) {
        const int t01 = (lane & 16) ? s1[v] : s0[v];
        const int t23 = (lane & 16) ? s3[v] : s2[v];
        ssel[v] = (lane & 32) ? t23 : t01;
    }

    // ---- issue ALL gathers up front ----
    // adjacency: int2/lane, 16 lanes cover 32 slots, 4 rows per instruction
    int2 a[K];
#pragma unroll
    for (int p = 0; p < K; ++p)
        a[p] = *reinterpret_cast<const int2*>(
            &adj[(size_t)ssel[p] * PAD_DEG + d * 2]);

    // embeddings: two float4/lane (row halves), 4 rows per instruction
    float4 e0[K], e1[K];
#pragma unroll
    for (int v = 0; v < K; ++v) {
        const float* base = &emb[(size_t)ssel[v] * F];
        e0[v] = *reinterpret_cast<const float4*>(base + d * 4);
        e1[v] = *reinterpret_cast<const float4*>(base + d * 4 + 64);
    }

    // ---- membership counts via ballot (4 rows per ballot) ----
    int cnt[K];
#pragma unroll
    for (int v = 0; v < K; ++v) cnt[v] = 0;

    const int sh = q * 16;        // my row's 16-bit slice of the ballot
#pragma unroll
    for (int p = 0; p < K; ++p) {
#pragma unroll
        for (int v = 0; v < K; ++v) {
            const unsigned long long m =
                __ballot(a[p].x == ssel[v] || a[p].y == ssel[v]);
            cnt[v] += (int)(((unsigned)(m >> sh) & 0xFFFFu) != 0);
        }
    }

    // ---- weights: w[v] = cnt[v] / sum(cnt)  (BETA = 1.0) ----
    int total = 0;
#pragma unroll
    for (int v = 0; v < K; ++v) total += cnt[v];
    const float inv = 1.0f / (float)total;   // >= 11 (self-loop in adj slot 0)

    // ---- weighted sum on prefetched fragments ----
    float4 acc0 = make_float4(0.f, 0.f, 0.f, 0.f);
    float4 acc1 = make_float4(0.f, 0.f, 0.f, 0.f);
#pragma unroll
    for (int v = 0; v < K; ++v) {
        const float w = (float)cnt[v] * inv;
        acc0.x = fmaf(w, e0[v].x, acc0.x);
        acc0.y = fmaf(w, e0[v].y, acc0.y);
        acc0.z = fmaf(w, e0[v].z, acc0.z);
        acc0.w = fmaf(w, e0[v].w, acc0.w);
        acc1.x = fmaf(w, e1[v].x, acc1.x);
        acc1.y = fmaf(w, e1[v].y, acc1.y);
        acc1.z = fmaf(w, e1[v].z, acc1.z);
        acc1.w = fmaf(w, e1[v].w, acc1.w);
    }

    // ---- store: row = r0+q, two contiguous 256 B segments per row ----
    const int row = r0 + q;
    float* obase = &out[(size_t)row * F];
    *reinterpret_cast<float4*>(obase + d * 4)      = acc0;
    *reinterpret_cast<float4*>(obase + d * 4 + 64) = acc1;
}

extern "C" void kernel_launch(void* const* d_in, const int* in_sizes, int n_in,
                              void* d_out, int out_size, void* d_ws, size_t ws_size,
                              hipStream_t stream) {
    const float* emb  = (const float*)d_in[0];
    const int*   samp = (const int*)d_in[1];
    const int*   adj  = (const int*)d_in[2];
    float*       outp = (float*)d_out;

    const int rows_per_block = 16;                // 4 waves x 4 rows
    dim3 grid(BATCH / rows_per_block);            // 1024 blocks
    dim3 block(256);
    WeightedAggregator_89489938580181_kernel<<<grid, block, 0, stream>>>(
        emb, samp, adj, outp);
}